// Round 3
// baseline (706.779 us; speedup 1.0000x reference)
//
#include <hip/hip_runtime.h>

// B=16384, T=56, F=56, H=20, 3H=60, FC1=128, NC=2
// R3: x-projection (x@Wih0^T + b_ih0) evicted from the scan into a separate
// memory-bound GEMM writing xp[B*T,60] into d_ws. Scan now holds only 60
// weight floats/lane (fully register-resident; R2's VGPR=116 proved wih0's 56
// regs forced in-loop weight reloads). Scan processes 2 batch elems/wave for
// 2x ILP on the latency-bound recurrence. Fallback to the R2 path if ws_size
// is too small for xp.

#define Bsz  16384
#define Tt   56
#define Ff   56
#define Hh   20
#define Gg   60
#define FC1n 128
#define THn  1120  // T*H
#define BT   (Bsz * Tt)

// ws float layout: [0..2239] weff, [2240..2241] beff, [2242..5601] WT (14*60*4),
// [5632 ..) xp (BT*60 floats)
#define WS_WEFF 0
#define WS_BEFF 2240
#define WS_WT   2242
#define WS_XP   5632
#define WS_NEED_BYTES ((size_t)(WS_XP + (size_t)BT * Gg) * 4)

typedef __attribute__((address_space(1))) const unsigned char gas_uchar;
typedef __attribute__((address_space(3))) unsigned char las_uchar;

__device__ __forceinline__ float rdlane(float v, int l) {
  return __uint_as_float(__builtin_amdgcn_readlane(__float_as_uint(v), l));
}
__device__ __forceinline__ float fast_rcp(float x) { return __builtin_amdgcn_rcpf(x); }
__device__ __forceinline__ float sigmoid_fast(float x) { return fast_rcp(1.0f + __expf(-x)); }
__device__ __forceinline__ float tanh_fast(float x) { return 1.0f - 2.0f * fast_rcp(1.0f + __expf(2.0f * x)); }

// ---------------- prep: W_eff, b_eff, and transposed/chunked W_ih0 ----------------
// W_eff[i][c] = sum_j W_fc1[j,i]*W_fc2[c,j]; b_eff[c] = b_fc2[c] + sum_j b_fc1[j]*W_fc2[c,j]
// WT[f4][g][c] = W_ih0[g][f4*4+c]  (chunked for wave-uniform float4 streaming)
__global__ void prep_all(const float* __restrict__ Wfc1, const float* __restrict__ bfc1,
                         const float* __restrict__ Wfc2, const float* __restrict__ bfc2,
                         const float* __restrict__ Wih0, float* __restrict__ ws) {
  int i = blockIdx.x * blockDim.x + threadIdx.x;
  if (i < THn) {
    float s0a = 0.f, s1a = 0.f, s0b = 0.f, s1b = 0.f;
    float s0c = 0.f, s1c = 0.f, s0d = 0.f, s1d = 0.f;
#pragma unroll 4
    for (int j = 0; j < FC1n; j += 4) {
      float wa = Wfc1[(j + 0) * THn + i];
      float wb = Wfc1[(j + 1) * THn + i];
      float wc = Wfc1[(j + 2) * THn + i];
      float wd = Wfc1[(j + 3) * THn + i];
      s0a = fmaf(wa, Wfc2[j + 0], s0a); s1a = fmaf(wa, Wfc2[FC1n + j + 0], s1a);
      s0b = fmaf(wb, Wfc2[j + 1], s0b); s1b = fmaf(wb, Wfc2[FC1n + j + 1], s1b);
      s0c = fmaf(wc, Wfc2[j + 2], s0c); s1c = fmaf(wc, Wfc2[FC1n + j + 2], s1c);
      s0d = fmaf(wd, Wfc2[j + 3], s0d); s1d = fmaf(wd, Wfc2[FC1n + j + 3], s1d);
    }
    ws[WS_WEFF + i * 2 + 0] = (s0a + s0b) + (s0c + s0d);
    ws[WS_WEFF + i * 2 + 1] = (s1a + s1b) + (s1c + s1d);
  } else if (i < THn + 2) {
    int c = i - THn;
    float s = bfc2[c];
    for (int j = 0; j < FC1n; ++j) s = fmaf(bfc1[j], Wfc2[c * FC1n + j], s);
    ws[WS_BEFF + c] = s;
  } else if (i < THn + 2 + 14 * Gg * 4) {
    int j = i - (THn + 2);          // j = f4*240 + g*4 + c
    int f4 = j / 240;
    int rem = j % 240;
    int g = rem / 4, c = rem % 4;
    ws[WS_WT + j] = Wih0[g * Ff + f4 * 4 + c];
  }
}

// ---------------- xproj: xp[row][g] = b_ih0[g] + sum_f x[row][f]*Wih0[g][f] ----------------
__global__ __launch_bounds__(256, 4) void xproj_kernel(
    const float* __restrict__ x, const float* __restrict__ bih0,
    const float* __restrict__ wschunk /* ws+WS_WT */, float* __restrict__ xp) {
  int row = blockIdx.x * 256 + threadIdx.x;  // 917504 rows exactly
  const float4* xr = (const float4*)(x + (size_t)row * Ff);
  const float4* wt = (const float4*)wschunk;  // [14][60] float4, wave-uniform reads
  float acc[Gg];
#pragma unroll
  for (int g = 0; g < Gg; ++g) acc[g] = bih0[g];
#pragma unroll 1
  for (int f4 = 0; f4 < 14; ++f4) {
    float4 xv = xr[f4];
    const float4* wb = wt + f4 * Gg;
#pragma unroll
    for (int g = 0; g < Gg; ++g) {
      float4 w = wb[g];
      acc[g] = fmaf(xv.x, w.x, fmaf(xv.y, w.y, fmaf(xv.z, w.z, fmaf(xv.w, w.w, acc[g]))));
    }
  }
  float4* out = (float4*)(xp + (size_t)row * Gg);
#pragma unroll
  for (int q = 0; q < 15; ++q)
    out[q] = make_float4(acc[4 * q], acc[4 * q + 1], acc[4 * q + 2], acc[4 * q + 3]);
}

// ---------------- scan (xp mode): 2 elems/wave ----------------
__global__ __launch_bounds__(256, 4) void gru_scan_xp(
    const float* __restrict__ xp,
    const float* __restrict__ Whh0, const float* __restrict__ bhh0,
    const float* __restrict__ Wih1, const float* __restrict__ bih1,
    const float* __restrict__ Whh1, const float* __restrict__ bhh1,
    const float* __restrict__ ws, float* __restrict__ y) {
  __shared__ float weff[2 * THn + 2];
  for (int idx = threadIdx.x; idx < 2 * THn + 2; idx += 256) weff[idx] = ws[idx];
  __syncthreads();

  const int lane = threadIdx.x & 63;
  const int wv = threadIdx.x >> 6;
  const int b0 = blockIdx.x * 8 + wv * 2;  // elems b0, b0+1
  const int g = (lane < Gg) ? lane : 0;

  float whh0r[Hh], wih1r[Hh], whh1r[Hh];
#pragma unroll
  for (int k = 0; k < Hh; ++k) whh0r[k] = Whh0[g * Hh + k];
#pragma unroll
  for (int k = 0; k < Hh; ++k) wih1r[k] = Wih1[g * Hh + k];
#pragma unroll
  for (int k = 0; k < Hh; ++k) whh1r[k] = Whh1[g * Hh + k];
  const float bh0 = bhh0[g], bi1 = bih1[g], bh1 = bhh1[g];

  float sA0[Hh], sA1[Hh];
#pragma unroll
  for (int k = 0; k < Hh; ++k) { sA0[k] = 0.f; sA1[k] = 0.f; }
  float hmA0 = 0.f, hmA1 = 0.f, hmB0 = 0.f, hmB1 = 0.f;
  float y00 = 0.f, y01 = 0.f, y10 = 0.f, y11 = 0.f;

  const int addrR = ((lane >= 40) ? (lane - 40) : lane) * 4;
  const int addrZ = ((lane >= 40) ? (lane - 20) : lane) * 4;
  const int jm = (lane >= 40 && lane < Gg) ? lane - 40 : 0;

  const float* xpr0 = xp + (size_t)b0 * (Tt * Gg) + g;
  const float* xpr1 = xpr0 + (size_t)(Tt * Gg);
  float xc0 = xpr0[0];
  float xc1 = xpr1[0];

#pragma unroll 1
  for (int t = 0; t < Tt; ++t) {
    float xn0 = xc0, xn1 = xc1;
    if (t < Tt - 1) {  // uniform branch; prefetch next step's xp
      xn0 = xpr0[(t + 1) * Gg];
      xn1 = xpr1[(t + 1) * Gg];
    }
    // ---- layer 0, elem 0 ----
    {
      float h0 = bh0, h1v = 0.f;
#pragma unroll
      for (int k = 0; k < Hh; k += 2) {
        h0 = fmaf(sA0[k + 0], whh0r[k + 0], h0);
        h1v = fmaf(sA0[k + 1], whh0r[k + 1], h1v);
      }
      float hg = h0 + h1v;
      float sg = sigmoid_fast(xc0 + hg);
      float rr = __uint_as_float(__builtin_amdgcn_ds_bpermute(addrR, __float_as_uint(sg)));
      float nn = tanh_fast(fmaf(rr, hg, xc0));
      float zz = __uint_as_float(__builtin_amdgcn_ds_bpermute(addrZ, __float_as_uint(sg)));
      hmA0 = fmaf(zz, hmA0 - nn, nn);
    }
    // ---- layer 0, elem 1 ----
    {
      float h0 = bh0, h1v = 0.f;
#pragma unroll
      for (int k = 0; k < Hh; k += 2) {
        h0 = fmaf(sA1[k + 0], whh0r[k + 0], h0);
        h1v = fmaf(sA1[k + 1], whh0r[k + 1], h1v);
      }
      float hg = h0 + h1v;
      float sg = sigmoid_fast(xc1 + hg);
      float rr = __uint_as_float(__builtin_amdgcn_ds_bpermute(addrR, __float_as_uint(sg)));
      float nn = tanh_fast(fmaf(rr, hg, xc1));
      float zz = __uint_as_float(__builtin_amdgcn_ds_bpermute(addrZ, __float_as_uint(sg)));
      hmA1 = fmaf(zz, hmA1 - nn, nn);
    }
    // broadcast h1-state to SGPRs
#pragma unroll
    for (int j = 0; j < Hh; ++j) sA0[j] = rdlane(hmA0, 40 + j);
#pragma unroll
    for (int j = 0; j < Hh; ++j) sA1[j] = rdlane(hmA1, 40 + j);
    // ---- layer 1, elem 0 ----
    {
      float a0 = bi1, a1 = 0.f;
#pragma unroll
      for (int k = 0; k < Hh; k += 2) {
        a0 = fmaf(sA0[k + 0], wih1r[k + 0], a0);
        a1 = fmaf(sA0[k + 1], wih1r[k + 1], a1);
      }
      float ig = a0 + a1;
      float h0 = bh1, h1v = 0.f;
#pragma unroll
      for (int k = 0; k < Hh; k += 2) {  // inline readlane: transient SGPR use
        h0 = fmaf(rdlane(hmB0, 40 + k), whh1r[k + 0], h0);
        h1v = fmaf(rdlane(hmB0, 41 + k), whh1r[k + 1], h1v);
      }
      float hg = h0 + h1v;
      float sg = sigmoid_fast(ig + hg);
      float rr = __uint_as_float(__builtin_amdgcn_ds_bpermute(addrR, __float_as_uint(sg)));
      float nn = tanh_fast(fmaf(rr, hg, ig));
      float zz = __uint_as_float(__builtin_amdgcn_ds_bpermute(addrZ, __float_as_uint(sg)));
      hmB0 = fmaf(zz, hmB0 - nn, nn);
    }
    // ---- layer 1, elem 1 ----
    {
      float a0 = bi1, a1 = 0.f;
#pragma unroll
      for (int k = 0; k < Hh; k += 2) {
        a0 = fmaf(sA1[k + 0], wih1r[k + 0], a0);
        a1 = fmaf(sA1[k + 1], wih1r[k + 1], a1);
      }
      float ig = a0 + a1;
      float h0 = bh1, h1v = 0.f;
#pragma unroll
      for (int k = 0; k < Hh; k += 2) {
        h0 = fmaf(rdlane(hmB1, 40 + k), whh1r[k + 0], h0);
        h1v = fmaf(rdlane(hmB1, 41 + k), whh1r[k + 1], h1v);
      }
      float hg = h0 + h1v;
      float sg = sigmoid_fast(ig + hg);
      float rr = __uint_as_float(__builtin_amdgcn_ds_bpermute(addrR, __float_as_uint(sg)));
      float nn = tanh_fast(fmaf(rr, hg, ig));
      float zz = __uint_as_float(__builtin_amdgcn_ds_bpermute(addrZ, __float_as_uint(sg)));
      hmB1 = fmaf(zz, hmB1 - nn, nn);
    }
    // ---- FC accumulation (one weff read serves both elems) ----
    {
      float2 wv2 = *(const float2*)&weff[(t * Hh + jm) * 2];
      y00 = fmaf(hmB0, wv2.x, y00);
      y01 = fmaf(hmB0, wv2.y, y01);
      y10 = fmaf(hmB1, wv2.x, y10);
      y11 = fmaf(hmB1, wv2.y, y11);
    }
    xc0 = xn0; xc1 = xn1;
  }

  if (!(lane >= 40 && lane < Gg)) { y00 = 0.f; y01 = 0.f; y10 = 0.f; y11 = 0.f; }
#pragma unroll
  for (int off = 32; off >= 1; off >>= 1) {
    y00 += __shfl_xor(y00, off, 64);
    y01 += __shfl_xor(y01, off, 64);
    y10 += __shfl_xor(y10, off, 64);
    y11 += __shfl_xor(y11, off, 64);
  }
  if (lane == 0) {
    float be0 = weff[WS_BEFF], be1 = weff[WS_BEFF + 1];
    float4 out = make_float4(y00 + be0, y01 + be1, y10 + be0, y11 + be1);
    *(float4*)(y + (size_t)b0 * 2) = out;  // covers elems b0, b0+1
  }
}

// ---------------- R2 fallback scan (used if ws too small for xp) ----------------
__global__ __launch_bounds__(256) void gru_scan_fb(
    const float* __restrict__ x,
    const float* __restrict__ Wih0, const float* __restrict__ Whh0,
    const float* __restrict__ bih0, const float* __restrict__ bhh0,
    const float* __restrict__ Wih1, const float* __restrict__ Whh1,
    const float* __restrict__ bih1, const float* __restrict__ bhh1,
    const float* __restrict__ ws, float* __restrict__ y) {
  __shared__ float weff[2 * THn];
  __shared__ __align__(16) float xstage[4][2][Ff];
  for (int idx = threadIdx.x; idx < 2 * THn; idx += 256) weff[idx] = ws[idx];
  __syncthreads();

  const int lane = threadIdx.x & 63;
  const int wv = threadIdx.x >> 6;
  const int b = blockIdx.x * 4 + wv;
  const int g = (lane < Gg) ? lane : 0;

  float wih0[Ff], whh0[Hh], wih1[Hh], whh1[Hh];
#pragma unroll
  for (int f = 0; f < Ff; ++f) wih0[f] = Wih0[g * Ff + f];
#pragma unroll
  for (int k = 0; k < Hh; ++k) whh0[k] = Whh0[g * Hh + k];
#pragma unroll
  for (int k = 0; k < Hh; ++k) wih1[k] = Wih1[g * Hh + k];
#pragma unroll
  for (int k = 0; k < Hh; ++k) whh1[k] = Whh1[g * Hh + k];
  const float bi0 = bih0[g], bh0 = bhh0[g], bi1 = bih1[g], bh1 = bhh1[g];

  float sA[Hh], sB[Hh];
#pragma unroll
  for (int k = 0; k < Hh; ++k) { sA[k] = 0.f; sB[k] = 0.f; }
  float hmA = 0.f, hmB = 0.f, y0 = 0.f, y1 = 0.f;

  const float* xrow = x + (size_t)b * (Tt * Ff);
  const int addrR = ((lane >= 40) ? (lane - 40) : lane) * 4;
  const int addrZ = ((lane >= 40) ? (lane - 20) : lane) * 4;
  const int jm = (lane >= 40 && lane < Gg) ? lane - 40 : 0;

  if (lane < 14) {
    __builtin_amdgcn_global_load_lds((gas_uchar*)(xrow + lane * 4),
                                     (las_uchar*)&xstage[wv][0][0], 16, 0, 0);
  }

#pragma unroll 1
  for (int t = 0; t < Tt; ++t) {
    const float* nxt = xrow + ((t < Tt - 1) ? Ff : 0);
    if (lane < 14) {
      __builtin_amdgcn_global_load_lds((gas_uchar*)(nxt + lane * 4),
                                       (las_uchar*)&xstage[wv][(t + 1) & 1][0], 16, 0, 0);
    }
    asm volatile("s_waitcnt vmcnt(1)" ::: "memory");
    const float4* xs = (const float4*)&xstage[wv][t & 1][0];
    {
      float a0 = bi0, a1 = 0.f, a2 = 0.f, a3 = 0.f;
#pragma unroll
      for (int i = 0; i < 14; ++i) {
        float4 xv = xs[i];
        a0 = fmaf(xv.x, wih0[4 * i + 0], a0);
        a1 = fmaf(xv.y, wih0[4 * i + 1], a1);
        a2 = fmaf(xv.z, wih0[4 * i + 2], a2);
        a3 = fmaf(xv.w, wih0[4 * i + 3], a3);
      }
      float ig = (a0 + a1) + (a2 + a3);
      float h0 = bh0, h1v = 0.f;
#pragma unroll
      for (int k = 0; k < Hh; k += 2) {
        h0 = fmaf(sA[k + 0], whh0[k + 0], h0);
        h1v = fmaf(sA[k + 1], whh0[k + 1], h1v);
      }
      float hg = h0 + h1v;
      float sg = sigmoid_fast(ig + hg);
      float rr = __uint_as_float(__builtin_amdgcn_ds_bpermute(addrR, __float_as_uint(sg)));
      float nn = tanh_fast(fmaf(rr, hg, ig));
      float zz = __uint_as_float(__builtin_amdgcn_ds_bpermute(addrZ, __float_as_uint(sg)));
      hmA = fmaf(zz, hmA - nn, nn);
#pragma unroll
      for (int j = 0; j < Hh; ++j) sA[j] = rdlane(hmA, 40 + j);
    }
    {
      float a0 = bi1, a1 = 0.f;
#pragma unroll
      for (int k = 0; k < Hh; k += 2) {
        a0 = fmaf(sA[k + 0], wih1[k + 0], a0);
        a1 = fmaf(sA[k + 1], wih1[k + 1], a1);
      }
      float ig = a0 + a1;
      float h0 = bh1, h1v = 0.f;
#pragma unroll
      for (int k = 0; k < Hh; k += 2) {
        h0 = fmaf(sB[k + 0], whh1[k + 0], h0);
        h1v = fmaf(sB[k + 1], whh1[k + 1], h1v);
      }
      float hg = h0 + h1v;
      float sg = sigmoid_fast(ig + hg);
      float rr = __uint_as_float(__builtin_amdgcn_ds_bpermute(addrR, __float_as_uint(sg)));
      float nn = tanh_fast(fmaf(rr, hg, ig));
      float zz = __uint_as_float(__builtin_amdgcn_ds_bpermute(addrZ, __float_as_uint(sg)));
      hmB = fmaf(zz, hmB - nn, nn);
#pragma unroll
      for (int j = 0; j < Hh; ++j) sB[j] = rdlane(hmB, 40 + j);
    }
    {
      float2 wv2 = *(const float2*)&weff[(t * Hh + jm) * 2];
      y0 = fmaf(hmB, wv2.x, y0);
      y1 = fmaf(hmB, wv2.y, y1);
    }
    xrow += Ff;
  }

  if (!(lane >= 40 && lane < Gg)) { y0 = 0.f; y1 = 0.f; }
#pragma unroll
  for (int off = 32; off >= 1; off >>= 1) {
    y0 += __shfl_xor(y0, off, 64);
    y1 += __shfl_xor(y1, off, 64);
  }
  if (lane == 0) {
    float be0 = ws[WS_BEFF + 0], be1 = ws[WS_BEFF + 1];
    float2 out = make_float2(y0 + be0, y1 + be1);
    *(float2*)(y + (size_t)b * 2) = out;
  }
}

extern "C" void kernel_launch(void* const* d_in, const int* in_sizes, int n_in,
                              void* d_out, int out_size, void* d_ws, size_t ws_size,
                              hipStream_t stream) {
  const float* x    = (const float*)d_in[0];
  const float* Wih0 = (const float*)d_in[1];
  const float* Whh0 = (const float*)d_in[2];
  const float* bih0 = (const float*)d_in[3];
  const float* bhh0 = (const float*)d_in[4];
  const float* Wih1 = (const float*)d_in[5];
  const float* Whh1 = (const float*)d_in[6];
  const float* bih1 = (const float*)d_in[7];
  const float* bhh1 = (const float*)d_in[8];
  const float* Wfc1 = (const float*)d_in[9];
  const float* bfc1 = (const float*)d_in[10];
  const float* Wfc2 = (const float*)d_in[11];
  const float* bfc2 = (const float*)d_in[12];
  float* ws = (float*)d_ws;
  float* y  = (float*)d_out;

  prep_all<<<18, 256, 0, stream>>>(Wfc1, bfc1, Wfc2, bfc2, Wih0, ws);

  if (ws_size >= WS_NEED_BYTES) {
    float* xp = ws + WS_XP;
    xproj_kernel<<<BT / 256, 256, 0, stream>>>(x, bih0, ws + WS_WT, xp);
    gru_scan_xp<<<Bsz / 8, 256, 0, stream>>>(xp, Whh0, bhh0, Wih1, bih1,
                                             Whh1, bhh1, ws, y);
  } else {
    gru_scan_fb<<<Bsz / 4, 256, 0, stream>>>(x, Wih0, Whh0, bih0, bhh0,
                                             Wih1, Whh1, bih1, bhh1, ws, y);
  }
}

// Round 4
// 643.833 us; speedup vs baseline: 1.0978x; 1.0978x over previous
//
#include <hip/hip_runtime.h>

// B=16384, T=56, F=56, H=20, 3H=60, FC1=128, NC=2
// R4: (1) xproj stages x through LDS (rows padded to 57 words -> conflict-free,
// coalesced HBM reads; fixes R3's 3.4x over-fetch). (2) scan takes 4 batch
// elems per wave with inline-transient readlane broadcasts (no persistent
// SGPR arrays) for 2x more ILP on the latency-bound recurrence.

#define Bsz  16384
#define Tt   56
#define Ff   56
#define Hh   20
#define Gg   60
#define FC1n 128
#define THn  1120  // T*H
#define BT   (Bsz * Tt)

// ws float layout: [0..2239] weff, [2240..2241] beff, [2242..5601] WT (14*60*4),
// [5632 ..) xp (BT*60 floats)
#define WS_WEFF 0
#define WS_BEFF 2240
#define WS_WT   2242
#define WS_XP   5632
#define WS_NEED_BYTES ((size_t)(WS_XP + (size_t)BT * Gg) * 4)

typedef __attribute__((address_space(1))) const unsigned char gas_uchar;
typedef __attribute__((address_space(3))) unsigned char las_uchar;

__device__ __forceinline__ float rdlane(float v, int l) {
  return __uint_as_float(__builtin_amdgcn_readlane(__float_as_uint(v), l));
}
__device__ __forceinline__ float bperm(int addr, float v) {
  return __uint_as_float(__builtin_amdgcn_ds_bpermute(addr, __float_as_uint(v)));
}
__device__ __forceinline__ float fast_rcp(float x) { return __builtin_amdgcn_rcpf(x); }
__device__ __forceinline__ float sigmoid_fast(float x) { return fast_rcp(1.0f + __expf(-x)); }
__device__ __forceinline__ float tanh_fast(float x) { return 1.0f - 2.0f * fast_rcp(1.0f + __expf(2.0f * x)); }

// dot of broadcast h (held on lanes 40..59 of hm) with per-lane 20-weight row
__device__ __forceinline__ float dot20(const float* w, float hm, float bias) {
  float a0 = bias, a1 = 0.f;
#pragma unroll
  for (int k = 0; k < Hh; k += 2) {
    a0 = fmaf(rdlane(hm, 40 + k), w[k + 0], a0);
    a1 = fmaf(rdlane(hm, 41 + k), w[k + 1], a1);
  }
  return a0 + a1;
}

__device__ __forceinline__ void gru_cell(float xg, float hg, int addrR, int addrZ, float& hm) {
  float sg = sigmoid_fast(xg + hg);     // r on lanes 0..19, z on 20..39
  float rr = bperm(addrR, sg);
  float nn = tanh_fast(fmaf(rr, hg, xg));
  float zz = bperm(addrZ, sg);
  hm = fmaf(zz, hm - nn, nn);           // n + z*(h-n)
}

// ---------------- prep: W_eff, b_eff, and transposed/chunked W_ih0 ----------------
__global__ void prep_all(const float* __restrict__ Wfc1, const float* __restrict__ bfc1,
                         const float* __restrict__ Wfc2, const float* __restrict__ bfc2,
                         const float* __restrict__ Wih0, float* __restrict__ ws) {
  int i = blockIdx.x * blockDim.x + threadIdx.x;
  if (i < THn) {
    float s0a = 0.f, s1a = 0.f, s0b = 0.f, s1b = 0.f;
    float s0c = 0.f, s1c = 0.f, s0d = 0.f, s1d = 0.f;
#pragma unroll 4
    for (int j = 0; j < FC1n; j += 4) {
      float wa = Wfc1[(j + 0) * THn + i];
      float wb = Wfc1[(j + 1) * THn + i];
      float wc = Wfc1[(j + 2) * THn + i];
      float wd = Wfc1[(j + 3) * THn + i];
      s0a = fmaf(wa, Wfc2[j + 0], s0a); s1a = fmaf(wa, Wfc2[FC1n + j + 0], s1a);
      s0b = fmaf(wb, Wfc2[j + 1], s0b); s1b = fmaf(wb, Wfc2[FC1n + j + 1], s1b);
      s0c = fmaf(wc, Wfc2[j + 2], s0c); s1c = fmaf(wc, Wfc2[FC1n + j + 2], s1c);
      s0d = fmaf(wd, Wfc2[j + 3], s0d); s1d = fmaf(wd, Wfc2[FC1n + j + 3], s1d);
    }
    ws[WS_WEFF + i * 2 + 0] = (s0a + s0b) + (s0c + s0d);
    ws[WS_WEFF + i * 2 + 1] = (s1a + s1b) + (s1c + s1d);
  } else if (i < THn + 2) {
    int c = i - THn;
    float s = bfc2[c];
    for (int j = 0; j < FC1n; ++j) s = fmaf(bfc1[j], Wfc2[c * FC1n + j], s);
    ws[WS_BEFF + c] = s;
  } else if (i < THn + 2 + 14 * Gg * 4) {
    int j = i - (THn + 2);          // j = f4*240 + g*4 + c
    int f4 = j / 240;
    int rem = j % 240;
    int g = rem / 4, c = rem % 4;
    ws[WS_WT + j] = Wih0[g * Ff + f4 * 4 + c];
  }
}

// ---------------- xproj v2: LDS-staged x ----------------
// Block = 256 rows. Stage 256x56 floats coalesced into LDS (rows padded to 57
// words: bank = 25*tid mod 32 -> conflict-free). Then thread=row computes all
// 60 gates with wave-uniform (scalarized) weight reads from ws+WS_WT.
#define PadW 57
__global__ __launch_bounds__(256, 2) void xproj_kernel(
    const float* __restrict__ x, const float* __restrict__ bih0,
    const float* __restrict__ wschunk /* ws+WS_WT */, float* __restrict__ xp) {
  __shared__ float xs[256 * PadW];  // 58368 B
  const int tid = threadIdx.x;
  const size_t blk0 = (size_t)blockIdx.x * 256;  // first row of this block

  // stage: 3584 float4 pieces; piece p covers row p/14, quad-col p%14
  const float4* xg = (const float4*)(x + blk0 * Ff);
#pragma unroll
  for (int i = 0; i < 14; ++i) {
    int p = i * 256 + tid;
    float4 v = xg[p];                 // coalesced 16B/lane
    int r = p / 14, c = p % 14;
    *(float4*)&xs[r * PadW + c * 4] = v;
  }
  __syncthreads();

  float acc[Gg];
#pragma unroll
  for (int g = 0; g < Gg; ++g) acc[g] = bih0[g];  // uniform -> s_load

  const float4* wt = (const float4*)wschunk;  // [14][60] float4, wave-uniform
#pragma unroll 1
  for (int f4 = 0; f4 < 14; ++f4) {
    float4 xv = *(const float4*)&xs[tid * PadW + f4 * 4];
    const float4* wb = wt + f4 * Gg;
#pragma unroll
    for (int g = 0; g < Gg; ++g) {
      float4 w = wb[g];
      acc[g] = fmaf(xv.x, w.x, fmaf(xv.y, w.y, fmaf(xv.z, w.z, fmaf(xv.w, w.w, acc[g]))));
    }
  }
  float4* out = (float4*)(xp + (blk0 + tid) * Gg);
#pragma unroll
  for (int q = 0; q < 15; ++q)
    out[q] = make_float4(acc[4 * q], acc[4 * q + 1], acc[4 * q + 2], acc[4 * q + 3]);
}

// ---------------- scan: 4 elems/wave, inline-transient broadcasts ----------------
__global__ __launch_bounds__(256, 4) void gru_scan_xp4(
    const float* __restrict__ xp,
    const float* __restrict__ Whh0, const float* __restrict__ bhh0,
    const float* __restrict__ Wih1, const float* __restrict__ bih1,
    const float* __restrict__ Whh1, const float* __restrict__ bhh1,
    const float* __restrict__ ws, float* __restrict__ y) {
  __shared__ float weff[2 * THn + 2];
  for (int idx = threadIdx.x; idx < 2 * THn + 2; idx += 256) weff[idx] = ws[idx];
  __syncthreads();

  const int lane = threadIdx.x & 63;
  const int wv = threadIdx.x >> 6;
  const int b0 = (blockIdx.x * 4 + wv) * 4;  // elems b0..b0+3
  const int g = (lane < Gg) ? lane : 0;

  float whh0r[Hh], wih1r[Hh], whh1r[Hh];
#pragma unroll
  for (int k = 0; k < Hh; ++k) whh0r[k] = Whh0[g * Hh + k];
#pragma unroll
  for (int k = 0; k < Hh; ++k) wih1r[k] = Wih1[g * Hh + k];
#pragma unroll
  for (int k = 0; k < Hh; ++k) whh1r[k] = Whh1[g * Hh + k];
  const float bh0 = bhh0[g], bi1 = bih1[g], bh1 = bhh1[g];

  float hmA[4] = {0.f, 0.f, 0.f, 0.f};
  float hmB[4] = {0.f, 0.f, 0.f, 0.f};
  float ya[4] = {0.f, 0.f, 0.f, 0.f};
  float yb[4] = {0.f, 0.f, 0.f, 0.f};

  const int addrR = ((lane >= 40) ? (lane - 40) : lane) * 4;
  const int addrZ = ((lane >= 40) ? (lane - 20) : lane) * 4;
  const int jm = (lane >= 40 && lane < Gg) ? lane - 40 : 0;

  const float* xpr[4];
  float xc[4], xn[4];
#pragma unroll
  for (int e = 0; e < 4; ++e) {
    xpr[e] = xp + (size_t)(b0 + e) * (Tt * Gg) + g;
    xc[e] = xpr[e][0];
  }

#pragma unroll 1
  for (int t = 0; t < Tt; ++t) {
    if (t < Tt - 1) {  // uniform branch: prefetch next step's xp
#pragma unroll
      for (int e = 0; e < 4; ++e) xn[e] = xpr[e][(t + 1) * Gg];
    }
    // layer 0 (xc already includes b_ih0)
#pragma unroll
    for (int e = 0; e < 4; ++e) {
      float hg = dot20(whh0r, hmA[e], bh0);
      gru_cell(xc[e], hg, addrR, addrZ, hmA[e]);
    }
    // layer 1
#pragma unroll
    for (int e = 0; e < 4; ++e) {
      float ig = dot20(wih1r, hmA[e], bi1);
      float hg = dot20(whh1r, hmB[e], bh1);
      gru_cell(ig, hg, addrR, addrZ, hmB[e]);
    }
    // FC accumulation (lane 40+j holds h2[t][j]; one weff read serves all elems)
    {
      float2 wv2 = *(const float2*)&weff[(t * Hh + jm) * 2];
#pragma unroll
      for (int e = 0; e < 4; ++e) {
        ya[e] = fmaf(hmB[e], wv2.x, ya[e]);
        yb[e] = fmaf(hmB[e], wv2.y, yb[e]);
      }
    }
#pragma unroll
    for (int e = 0; e < 4; ++e) xc[e] = xn[e];
  }

  const bool active = (lane >= 40 && lane < Gg);
#pragma unroll
  for (int e = 0; e < 4; ++e) {
    if (!active) { ya[e] = 0.f; yb[e] = 0.f; }
  }
#pragma unroll
  for (int off = 32; off >= 1; off >>= 1) {
#pragma unroll
    for (int e = 0; e < 4; ++e) {
      ya[e] += __shfl_xor(ya[e], off, 64);
      yb[e] += __shfl_xor(yb[e], off, 64);
    }
  }
  if (lane == 0) {
    float be0 = weff[WS_BEFF], be1 = weff[WS_BEFF + 1];
    float4 o0 = make_float4(ya[0] + be0, yb[0] + be1, ya[1] + be0, yb[1] + be1);
    float4 o1 = make_float4(ya[2] + be0, yb[2] + be1, ya[3] + be0, yb[3] + be1);
    float4* yo = (float4*)(y + (size_t)b0 * 2);
    yo[0] = o0;
    yo[1] = o1;
  }
}

// ---------------- fallback scan (ws too small for xp) ----------------
__global__ __launch_bounds__(256) void gru_scan_fb(
    const float* __restrict__ x,
    const float* __restrict__ Wih0, const float* __restrict__ Whh0,
    const float* __restrict__ bih0, const float* __restrict__ bhh0,
    const float* __restrict__ Wih1, const float* __restrict__ Whh1,
    const float* __restrict__ bih1, const float* __restrict__ bhh1,
    const float* __restrict__ ws, float* __restrict__ y) {
  __shared__ float weff[2 * THn];
  __shared__ __align__(16) float xstage[4][2][Ff];
  for (int idx = threadIdx.x; idx < 2 * THn; idx += 256) weff[idx] = ws[idx];
  __syncthreads();

  const int lane = threadIdx.x & 63;
  const int wv = threadIdx.x >> 6;
  const int b = blockIdx.x * 4 + wv;
  const int g = (lane < Gg) ? lane : 0;

  float wih0[Ff], whh0[Hh], wih1[Hh], whh1[Hh];
#pragma unroll
  for (int f = 0; f < Ff; ++f) wih0[f] = Wih0[g * Ff + f];
#pragma unroll
  for (int k = 0; k < Hh; ++k) whh0[k] = Whh0[g * Hh + k];
#pragma unroll
  for (int k = 0; k < Hh; ++k) wih1[k] = Wih1[g * Hh + k];
#pragma unroll
  for (int k = 0; k < Hh; ++k) whh1[k] = Whh1[g * Hh + k];
  const float bi0 = bih0[g], bh0 = bhh0[g], bi1 = bih1[g], bh1 = bhh1[g];

  float sA[Hh], sB[Hh];
#pragma unroll
  for (int k = 0; k < Hh; ++k) { sA[k] = 0.f; sB[k] = 0.f; }
  float hmA = 0.f, hmB = 0.f, y0 = 0.f, y1 = 0.f;

  const float* xrow = x + (size_t)b * (Tt * Ff);
  const int addrR = ((lane >= 40) ? (lane - 40) : lane) * 4;
  const int addrZ = ((lane >= 40) ? (lane - 20) : lane) * 4;
  const int jm = (lane >= 40 && lane < Gg) ? lane - 40 : 0;

  if (lane < 14) {
    __builtin_amdgcn_global_load_lds((gas_uchar*)(xrow + lane * 4),
                                     (las_uchar*)&xstage[wv][0][0], 16, 0, 0);
  }

#pragma unroll 1
  for (int t = 0; t < Tt; ++t) {
    const float* nxt = xrow + ((t < Tt - 1) ? Ff : 0);
    if (lane < 14) {
      __builtin_amdgcn_global_load_lds((gas_uchar*)(nxt + lane * 4),
                                       (las_uchar*)&xstage[wv][(t + 1) & 1][0], 16, 0, 0);
    }
    asm volatile("s_waitcnt vmcnt(1)" ::: "memory");
    const float4* xs = (const float4*)&xstage[wv][t & 1][0];
    {
      float a0 = bi0, a1 = 0.f, a2 = 0.f, a3 = 0.f;
#pragma unroll
      for (int i = 0; i < 14; ++i) {
        float4 xv = xs[i];
        a0 = fmaf(xv.x, wih0[4 * i + 0], a0);
        a1 = fmaf(xv.y, wih0[4 * i + 1], a1);
        a2 = fmaf(xv.z, wih0[4 * i + 2], a2);
        a3 = fmaf(xv.w, wih0[4 * i + 3], a3);
      }
      float ig = (a0 + a1) + (a2 + a3);
      float h0 = bh0, h1v = 0.f;
#pragma unroll
      for (int k = 0; k < Hh; k += 2) {
        h0 = fmaf(sA[k + 0], whh0[k + 0], h0);
        h1v = fmaf(sA[k + 1], whh0[k + 1], h1v);
      }
      float hg = h0 + h1v;
      gru_cell(ig, hg, addrR, addrZ, hmA);
#pragma unroll
      for (int j = 0; j < Hh; ++j) sA[j] = rdlane(hmA, 40 + j);
    }
    {
      float a0 = bi1, a1 = 0.f;
#pragma unroll
      for (int k = 0; k < Hh; k += 2) {
        a0 = fmaf(sA[k + 0], wih1[k + 0], a0);
        a1 = fmaf(sA[k + 1], wih1[k + 1], a1);
      }
      float ig = a0 + a1;
      float h0 = bh1, h1v = 0.f;
#pragma unroll
      for (int k = 0; k < Hh; k += 2) {
        h0 = fmaf(sB[k + 0], whh1[k + 0], h0);
        h1v = fmaf(sB[k + 1], whh1[k + 1], h1v);
      }
      float hg = h0 + h1v;
      gru_cell(ig, hg, addrR, addrZ, hmB);
#pragma unroll
      for (int j = 0; j < Hh; ++j) sB[j] = rdlane(hmB, 40 + j);
    }
    {
      float2 wv2 = *(const float2*)&weff[(t * Hh + jm) * 2];
      y0 = fmaf(hmB, wv2.x, y0);
      y1 = fmaf(hmB, wv2.y, y1);
    }
    xrow += Ff;
  }

  if (!(lane >= 40 && lane < Gg)) { y0 = 0.f; y1 = 0.f; }
#pragma unroll
  for (int off = 32; off >= 1; off >>= 1) {
    y0 += __shfl_xor(y0, off, 64);
    y1 += __shfl_xor(y1, off, 64);
  }
  if (lane == 0) {
    float be0 = ws[WS_BEFF + 0], be1 = ws[WS_BEFF + 1];
    float2 out = make_float2(y0 + be0, y1 + be1);
    *(float2*)(y + (size_t)b * 2) = out;
  }
}

extern "C" void kernel_launch(void* const* d_in, const int* in_sizes, int n_in,
                              void* d_out, int out_size, void* d_ws, size_t ws_size,
                              hipStream_t stream) {
  const float* x    = (const float*)d_in[0];
  const float* Wih0 = (const float*)d_in[1];
  const float* Whh0 = (const float*)d_in[2];
  const float* bih0 = (const float*)d_in[3];
  const float* bhh0 = (const float*)d_in[4];
  const float* Wih1 = (const float*)d_in[5];
  const float* Whh1 = (const float*)d_in[6];
  const float* bih1 = (const float*)d_in[7];
  const float* bhh1 = (const float*)d_in[8];
  const float* Wfc1 = (const float*)d_in[9];
  const float* bfc1 = (const float*)d_in[10];
  const float* Wfc2 = (const float*)d_in[11];
  const float* bfc2 = (const float*)d_in[12];
  float* ws = (float*)d_ws;
  float* y  = (float*)d_out;

  prep_all<<<18, 256, 0, stream>>>(Wfc1, bfc1, Wfc2, bfc2, Wih0, ws);

  if (ws_size >= WS_NEED_BYTES) {
    float* xp = ws + WS_XP;
    xproj_kernel<<<BT / 256, 256, 0, stream>>>(x, bih0, ws + WS_WT, xp);
    gru_scan_xp4<<<Bsz / 16, 256, 0, stream>>>(xp, Whh0, bhh0, Wih1, bih1,
                                               Whh1, bhh1, ws, y);
  } else {
    gru_scan_fb<<<Bsz / 4, 256, 0, stream>>>(x, Wih0, Whh0, bih0, bhh0,
                                             Wih1, Whh1, bih1, bhh1, ws, y);
  }
}